// Round 17
// baseline (283.476 us; speedup 1.0000x reference)
//
#include <hip/hip_runtime.h>

// ---------------------------------------------------------------------------
// Transformer-XL relative-position MHA.  b=4, s=1024, H=16, dk=64.
// Inputs fp32, OUTPUT fp32.  Round 26 (base R25: attn 74.5us):
//  - x bf16 pre-conversion ELIMINATED: gemm_fused A0 paths (QKV, U) stage
//    fp32 x directly with in-kernel cvt (reg-stage -> cvt8 -> swizzled
//    ds_write, the proven gemm_out B-path).  cvtprep loses its largest slice
//    (16MB read + 8MB write) and the dependency chain shortens.
//  - attn / gemm_out identical to R25 (sliding-P ring, prescale, diag-mask,
//    LPT queue, V-hoist, setprio).
// ---------------------------------------------------------------------------

typedef __attribute__((ext_vector_type(8))) short short8;
typedef __attribute__((ext_vector_type(4))) float f32x4;

#define KD 1024

__device__ __forceinline__ float bf2f(short s) {
    unsigned int u = ((unsigned int)(unsigned short)s) << 16;
    return __builtin_bit_cast(float, u);
}
__device__ __forceinline__ short f2bf(float f) {
    unsigned int u = __builtin_bit_cast(unsigned int, f);
    u = u + 0x7fffu + ((u >> 16) & 1u);
    return (short)(u >> 16);
}
__device__ __forceinline__ short8 cvt8(const float* p) {
    f32x4 a = *(const f32x4*)p;
    f32x4 b = *(const f32x4*)(p + 4);
    short8 r;
    r[0] = f2bf(a[0]); r[1] = f2bf(a[1]); r[2] = f2bf(a[2]); r[3] = f2bf(a[3]);
    r[4] = f2bf(b[0]); r[5] = f2bf(b[1]); r[6] = f2bf(b[2]); r[7] = f2bf(b[3]);
    return r;
}

typedef const __attribute__((address_space(1))) void gas_void;
typedef __attribute__((address_space(3))) void las_void;
__device__ __forceinline__ void async16(const void* g, void* l) {
    __builtin_amdgcn_global_load_lds((gas_void*)g, (las_void*)l, 16, 0, 0);
}

// ---- DPP row (16-lane) reductions: VALU pipe, no LDS ----
template <int CTRL>
__device__ __forceinline__ float dpp_rotf(float v) {
    return __builtin_bit_cast(float, __builtin_amdgcn_update_dpp(
        0, __builtin_bit_cast(int, v), CTRL, 0xF, 0xF, true));
}
__device__ __forceinline__ float row_max16(float v) {
    v = fmaxf(v, dpp_rotf<0x128>(v));   // row_ror:8
    v = fmaxf(v, dpp_rotf<0x124>(v));   // row_ror:4
    v = fmaxf(v, dpp_rotf<0x122>(v));   // row_ror:2
    v = fmaxf(v, dpp_rotf<0x121>(v));   // row_ror:1
    return v;
}
__device__ __forceinline__ float row_sum16(float v) {
    v += dpp_rotf<0x128>(v);
    v += dpp_rotf<0x124>(v);
    v += dpp_rotf<0x122>(v);
    v += dpp_rotf<0x121>(v);
    return v;
}

// ---------------- fused cvt (y<4: Wq,Wk,Wv,R) + prep (y==4) ----------------
struct CvtJobs { const float* src[4]; short* dst[4]; int n8[4]; };

__global__ __launch_bounds__(256) void cvtprep_kernel(
    CvtJobs j,
    const float* __restrict__ Wr, const float* __restrict__ br,
    const float* __restrict__ ru, const float* __restrict__ rv,
    short* __restrict__ wrubf, short* __restrict__ wrvbf,
    float* __restrict__ ub, float* __restrict__ vb,
    unsigned int* __restrict__ qcount) {
    const int y = blockIdx.y, tid = threadIdx.x;
    if (y < 4) {
        const int t = blockIdx.x * 256 + tid;
        if (t < j.n8[y]) *(short8*)&j.dst[y][t * 8] = cvt8(&j.src[y][t * 8]);
        return;
    }
    // prep: fold rel_u/rel_v into Wr; emit bf16 weight rows [h][k]
    if (blockIdx.x >= 64) return;
    if (blockIdx.x == 0 && tid == 0) *qcount = 0;   // init attn work queue
    const int idx = blockIdx.x * 256 + tid;  // 0..16383
    const int h = idx >> 10, k = idx & 1023;
    float su = 0.f, sv = 0.f;
    for (int d = 0; d < 64; ++d) {
        const float w = Wr[(size_t)(h * 64 + d) * 1024 + k];
        su += ru[h * 64 + d] * w;
        sv += rv[h * 64 + d] * w;
    }
    wrubf[h * 1024 + k] = f2bf(su);
    wrvbf[h * 1024 + k] = f2bf(sv);
    if (idx < 16) {
        float bu = 0.f, bv2 = 0.f;
        for (int d = 0; d < 64; ++d) {
            bu += ru[idx * 64 + d] * br[idx * 64 + d];
            bv2 += rv[idx * 64 + d] * br[idx * 64 + d];
        }
        ub[idx] = bu; vb[idx] = bv2;
    }
}

// ---------------- fused projection GEMM (BK=64, 2 barriers, swizzled) ----------------
struct Task { const short* W; const float* bias; short* out; int mode; };
struct Tasks { Task t[6]; };

// y<24: QKV from fp32 x (in-kernel cvt); y=24..25: P from A1 bf16;
// y=26: U from fp32 x (N=16, f32 out); y=27 (x<8): Bv from A1 (N=16, f32 out).
// mode 0: (b,H,s,dk) bf16  1: (b,H,dk,s) bf16  2: (H,s,dk) bf16
// mode 3: U f32   4: Bv f32.   q/U/Bv epilogues scaled by 0.125 (1/sqrt dk).
__global__ __launch_bounds__(256) void gemm_fused(
    const float* __restrict__ X, const short* __restrict__ A1, Tasks tasks) {
    __shared__ short As[128 * 64];
    __shared__ short Bs[128 * 64];
    const int tid  = threadIdx.x;
    const int wave = tid >> 6, lane = tid & 63;
    const int y    = blockIdx.y;
    bool a_fp32; int m0, n0, tksel;
    if (y < 24)      { a_fp32 = true;  m0 = blockIdx.x * 128; n0 = (y & 7) * 128; tksel = y >> 3; }
    else if (y < 26) { const int q = (y - 24) * 32 + blockIdx.x;
                       a_fp32 = false; m0 = (q >> 3) * 128; n0 = (q & 7) * 128; tksel = 3; }
    else if (y == 26){ a_fp32 = true;  m0 = blockIdx.x * 128; n0 = 0; tksel = 4; }
    else             { if (blockIdx.x >= 8) return;
                       a_fp32 = false; m0 = blockIdx.x * 128; n0 = 0; tksel = 5; }
    const Task tk  = tasks.t[tksel];
    const short* W = tk.W;
    const float oscale = (tksel == 0 || tksel >= 4) ? 0.125f : 1.0f;

    f32x4 acc[4][4];
#pragma unroll
    for (int i = 0; i < 4; ++i)
#pragma unroll
        for (int j = 0; j < 4; ++j) acc[i][j] = (f32x4){0.f, 0.f, 0.f, 0.f};

    const int wm = wave >> 1, wn = wave & 1;
    const int fr_row = lane & 15, fr_k = (lane >> 4) * 8;
    const int arow = tid >> 1, ahalf = tid & 1;   // fp32-A staging geometry

    for (int kt = 0; kt < KD / 64; ++kt) {
        const int k0 = kt * 64;
        // B staging (always bf16 async16): linear dest + inv-swizzled source col
#pragma unroll
        for (int i = 0; i < 4; ++i) {
            const int c = (i * 4 + wave) * 64 + lane;
            const int row = c >> 3, col = ((c & 7) ^ (row & 7)) * 8;
            async16(W + (size_t)(n0 + row) * KD + k0 + col, &Bs[(i * 4 + wave) * 512]);
        }
        // A staging
        if (a_fp32) {
            // reg-stage fp32 x -> bf16 swizzled LDS (2 threads/row, 32 cols each)
            const float* xp = X + (size_t)(m0 + arow) * KD + k0 + ahalf * 32;
            short* dst = &As[arow * 64];
#pragma unroll
            for (int u2 = 0; u2 < 4; ++u2) {
                short8 v = cvt8(xp + u2 * 8);
                *(short8*)&dst[(((ahalf * 4 + u2) ^ (arow & 7)) << 3)] = v;
            }
        } else {
#pragma unroll
            for (int i = 0; i < 4; ++i) {
                const int c = (i * 4 + wave) * 64 + lane;
                const int row = c >> 3, col = ((c & 7) ^ (row & 7)) * 8;
                async16(A1 + (size_t)(m0 + row) * KD + k0 + col, &As[(i * 4 + wave) * 512]);
            }
        }
        __syncthreads();
#pragma unroll
        for (int ks = 0; ks < 64; ks += 32) {
            const int un = (ks + fr_k) >> 3;
            short8 a[4], bfrag[4];
#pragma unroll
            for (int mi = 0; mi < 4; ++mi) {
                const int R = wm * 64 + mi * 16 + fr_row;
                a[mi] = *(const short8*)&As[R * 64 + ((un ^ (R & 7)) << 3)];
            }
#pragma unroll
            for (int ni = 0; ni < 4; ++ni) {
                const int R = wn * 64 + ni * 16 + fr_row;
                bfrag[ni] = *(const short8*)&Bs[R * 64 + ((un ^ (R & 7)) << 3)];
            }
#pragma unroll
            for (int mi = 0; mi < 4; ++mi)
#pragma unroll
                for (int ni = 0; ni < 4; ++ni)
                    acc[mi][ni] = __builtin_amdgcn_mfma_f32_16x16x32_bf16(a[mi], bfrag[ni], acc[mi][ni], 0, 0, 0);
        }
        __syncthreads();
    }

    const int mode = tk.mode;
#pragma unroll
    for (int ni = 0; ni < 4; ++ni) {
        const int n = n0 + wn * 64 + ni * 16 + fr_row;
        if (mode >= 3 && n >= 16) continue;
        const float bias = tk.bias[n];
#pragma unroll
        for (int mi = 0; mi < 4; ++mi) {
            const int mbase = m0 + wm * 64 + mi * 16 + (lane >> 4) * 4;
#pragma unroll
            for (int r = 0; r < 4; ++r) {
                const int m = mbase + r;
                const float val = (acc[mi][ni][r] + bias) * oscale;
                if (mode == 0)
                    tk.out[(((size_t)(m >> 10) * 16 + (n >> 6)) * 1024 + (m & 1023)) * 64 + (n & 63)] = f2bf(val);
                else if (mode == 1)
                    tk.out[(((size_t)(m >> 10) * 16 + (n >> 6)) * 64 + (n & 63)) * 1024 + (m & 1023)] = f2bf(val);
                else if (mode == 2)
                    tk.out[((size_t)(n >> 6) * 1024 + m) * 64 + (n & 63)] = f2bf(val);
                else if (mode == 3)
                    ((float*)tk.out)[((size_t)(m >> 10) * 16 + n) * 1024 + (m & 1023)] = val;
                else
                    ((float*)tk.out)[(size_t)n * 1024 + m] = val;
            }
        }
    }
}

// Final GEMM: A bf16 (vw), W = Wo FP32 (converted on the fly into swizzled
// bf16 LDS), out FP32 row-major.  128x64 tile, grid 32x16 = 512 blocks.
__global__ __launch_bounds__(256) void gemm_out(const short* __restrict__ A,
                                                const float* __restrict__ W,
                                                const float* __restrict__ bias,
                                                float* __restrict__ out) {
    __shared__ short As[128 * 64];
    __shared__ short Bs[64 * 64];
    const int tid  = threadIdx.x;
    const int wave = tid >> 6, lane = tid & 63;
    const int m0   = blockIdx.x * 128;
    const int n0   = blockIdx.y * 64;

    f32x4 acc[4][2];
#pragma unroll
    for (int i = 0; i < 4; ++i)
#pragma unroll
        for (int j = 0; j < 2; ++j) acc[i][j] = (f32x4){0.f, 0.f, 0.f, 0.f};

    const int wm = wave >> 1, wn = wave & 1;
    const int fr_row = lane & 15, fr_k = (lane >> 4) * 8;
    const int brow = tid >> 2, bcol16 = (tid & 3) * 16;   // B staging geometry

    for (int kt = 0; kt < KD / 64; ++kt) {
        const int k0 = kt * 64;
        // A: async16 staging, swizzled source col
#pragma unroll
        for (int i = 0; i < 4; ++i) {
            const int c = (i * 4 + wave) * 64 + lane;
            const int row = c >> 3, col = ((c & 7) ^ (row & 7)) * 8;
            async16(A + (size_t)(m0 + row) * KD + k0 + col, &As[(i * 4 + wave) * 512]);
        }
        // B: reg-staged Wo fp32 -> bf16, XOR-swizzled units (16B units)
        {
            const float* wp = W + (size_t)(n0 + brow) * KD + k0 + bcol16;
            short8 v0 = cvt8(wp);
            short8 v1 = cvt8(wp + 8);
            const int u0 = bcol16 >> 3;     // 0,2,4,6
            short* dst = &Bs[brow * 64];
            *(short8*)&dst[((u0 ^ (brow & 7)) << 3)]       = v0;
            *(short8*)&dst[(((u0 + 1) ^ (brow & 7)) << 3)] = v1;
        }
        __syncthreads();
#pragma unroll
        for (int ks = 0; ks < 64; ks += 32) {
            const int un = (ks + fr_k) >> 3;
            short8 a[4], bfrag[2];
#pragma unroll
            for (int mi = 0; mi < 4; ++mi) {
                const int R = wm * 64 + mi * 16 + fr_row;
                a[mi] = *(const short8*)&As[R * 64 + ((un ^ (R & 7)) << 3)];
            }
#pragma unroll
            for (int ni = 0; ni < 2; ++ni) {
                const int R = wn * 32 + ni * 16 + fr_row;
                bfrag[ni] = *(const short8*)&Bs[R * 64 + ((un ^ (R & 7)) << 3)];
            }
#pragma unroll
            for (int mi = 0; mi < 4; ++mi)
#pragma unroll
                for (int ni = 0; ni < 2; ++ni)
                    acc[mi][ni] = __builtin_amdgcn_mfma_f32_16x16x32_bf16(a[mi], bfrag[ni], acc[mi][ni], 0, 0, 0);
        }
        __syncthreads();
    }

#pragma unroll
    for (int ni = 0; ni < 2; ++ni) {
        const int n = n0 + wn * 32 + ni * 16 + fr_row;
        const float bv = bias[n];
#pragma unroll
        for (int mi = 0; mi < 4; ++mi) {
            const int mbase = m0 + wm * 64 + mi * 16 + (lane >> 4) * 4;
#pragma unroll
            for (int r = 0; r < 4; ++r)
                out[(size_t)(mbase + r) * 1024 + n] = acc[mi][ni][r] + bv;
        }
    }
}

// ---------------- flash attention (sliding-P ring + LPT queue) ----------------
// LDS (exactly 40,960 B):
//   Ks[64x64] sh (swizzled, gload_lds-staged)             8,192 B
//   Ps2[2][64x64] sh ring (swizzled; window slides 64/iter) 16,384 B
//   Band2[64x64] f32, pre-shifted [qrow][j], swizzled     16,384 B (Pls alias)
// Iter jt reads P rows [l_lo,l_lo+128): lower half in slot jt&1, upper in
// (jt+1)&1; prefetch stages only the NEW 64 rows into slot jt&1 (post-B2).
// Longest-first LPT queue; V hoisted pre-B2; setprio around MFMA clusters;
// scores pre-scaled (0.125 folded into q/U/Bv); mask only on diagonal tile.
__global__ __launch_bounds__(256) void attn_kernel(
    const short* __restrict__ q_ws, const short* __restrict__ k_ws,
    const short* __restrict__ v_ws, const short* __restrict__ p_ws,
    const float* __restrict__ U_ws, const float* __restrict__ Bv_ws,
    short* __restrict__ vw, unsigned int* __restrict__ qcount) {
    __shared__ short Ks[64 * 64];
    __shared__ short Ps2[2][64 * 64];
    __shared__ float Band2[64 * 64];
    short* Pls = (short*)Band2;        // stride 128 sh, swizzled

    const int tid = threadIdx.x;
    const int w = tid >> 6, lane = tid & 63;

    // ---- pop work item (longest-first) ----
    if (tid == 0) *(int*)&Band2[0] = (int)atomicAdd(qcount, 1u);
    __syncthreads();
    const int it = *(const int*)&Band2[0];
    const int bx = 15 - (it >> 6);            // 64 longest items first
    const int g  = it & 63;                   // (b,h) group
    const int h = g & 15, b = g >> 4;
    const int i0 = bx * 64;
    const int bh = b * 16 + h;
    const int fr_row = lane & 15, fr_q = lane >> 4, fr_k = fr_q * 8;
    const int lr = lane >> 3, lc = lane & 7;  // staging geometry (8 rows/1KB chunk)

    short8 qfrag[2];
    {
        const short* qrow = q_ws + ((size_t)bh * 1024 + i0 + w * 16 + fr_row) * 64;
        qfrag[0] = *(const short8*)&qrow[fr_k];
        qfrag[1] = *(const short8*)&qrow[32 + fr_k];
    }

    float m_run[4], l_run[4];
    f32x4 o_acc[4];
#pragma unroll
    for (int r2 = 0; r2 < 4; ++r2) { m_run[r2] = -1e30f; l_run[r2] = 0.f; }
#pragma unroll
    for (int dt = 0; dt < 4; ++dt) o_acc[dt] = (f32x4){0.f, 0.f, 0.f, 0.f};

    const int tt0 = 3 - w;
    const short* krowbase = k_ws + (size_t)bh * 1024 * 64;  // (j, d)
    const short* vrowbase = v_ws + (size_t)bh * 64 * 1024;  // (d, j)
    const short* prowbase = p_ws + (size_t)h * 1024 * 64;   // (l, d)

    // ---- prologue: issue K(0) + BOTH P halves for iter 0 ----
    {
        const int l_lo0 = 960 - i0;
#pragma unroll
        for (int i = 0; i < 2; ++i) {
            const int R = (w * 2 + i) * 8 + lr;
            async16(krowbase + (size_t)R * 64 + ((lc ^ (R & 7)) * 8), &Ks[(w * 2 + i) * 512]);
        }
#pragma unroll
        for (int i = 0; i < 4; ++i) {
            const int c = w * 4 + i;          // chunk 0..15; slot c>>3, 8 rows each
            const int R = c * 8 + lr;         // 0..127
            int gl = l_lo0 + R; gl = gl > 1023 ? 1023 : gl;
            async16(prowbase + (size_t)gl * 64 + ((lc ^ (R & 7)) * 8),
                    &Ps2[c >> 3][(c & 7) * 512]);
        }
    }

    for (int jt = 0; jt <= bx; ++jt) {
        const int j0 = jt * 64;
        const int l_lo = j0 - i0 + 960;

        // B1: K(jt) + P halves landed + all waves synced
        asm volatile("s_waitcnt vmcnt(0)" ::: "memory");
        __builtin_amdgcn_s_barrier();
        asm volatile("" ::: "memory");

        // hoisted U / Bv loads (pre-scaled by 0.125 in projection)
        float uv[4];
#pragma unroll
        for (int tt = 0; tt < 4; ++tt) uv[tt] = U_ws[bh * 1024 + j0 + tt * 16 + fr_row];
        float bvv[5];
#pragma unroll
        for (int u = 0; u < 5; ++u) {
            int l = l_lo + (tt0 + u) * 16 + fr_row;
            l = l > 1023 ? 1023 : l;
            bvv[u] = Bv_ws[h * 1024 + l];
        }

        // QK^T + relative-band MFMAs (swizzled LDS reads; P via 2-slot ring)
        f32x4 qk[4], bd[5];
#pragma unroll
        for (int tt = 0; tt < 4; ++tt) qk[tt] = (f32x4){0.f, 0.f, 0.f, 0.f};
#pragma unroll
        for (int u = 0; u < 5; ++u) bd[u] = (f32x4){0.f, 0.f, 0.f, 0.f};

        __builtin_amdgcn_s_setprio(1);
#pragma unroll
        for (int c = 0; c < 2; ++c) {
            const int col = c * 4 + fr_q;
#pragma unroll
            for (int tt = 0; tt < 4; ++tt) {
                const int R = tt * 16 + fr_row;
                short8 kf = *(const short8*)&Ks[R * 64 + ((col ^ (R & 7)) << 3)];
                qk[tt] = __builtin_amdgcn_mfma_f32_16x16x32_bf16(qfrag[c], kf, qk[tt], 0, 0, 0);
            }
#pragma unroll
            for (int u = 0; u < 5; ++u) {
                const int R = (tt0 + u) * 16 + fr_row;      // 0..127 in window
                const int slot = (jt + (R >> 6)) & 1;
                const int r6 = R & 63;
                short8 pf = *(const short8*)&Ps2[slot][r6 * 64 + ((col ^ (r6 & 7)) << 3)];
                bd[u] = __builtin_amdgcn_mfma_f32_16x16x32_bf16(qfrag[c], pf, bd[u], 0, 0, 0);
            }
        }
        __builtin_amdgcn_s_setprio(0);

        // V global->reg, issued BEFORE B2 (global-only: no barrier hazard)
        const short* vjt = vrowbase + j0;
        short8 vregA[4], vregB[4];
#pragma unroll
        for (int dt = 0; dt < 4; ++dt)
            vregA[dt] = *(const short8*)&vjt[(size_t)(dt * 16 + fr_row) * 1024 + fr_k];
#pragma unroll
        for (int dt = 0; dt < 4; ++dt)
            vregB[dt] = *(const short8*)&vjt[(size_t)(dt * 16 + fr_row) * 1024 + 32 + fr_k];

        // B2: all waves done reading Ks/Ps2 -> safe to overwrite via prefetch
        asm volatile("" ::: "memory");
        __builtin_amdgcn_s_barrier();
        asm volatile("" ::: "memory");

        if (jt < bx) {   // prefetch K(jt+1) + ONLY the new P half
            const int j0n = j0 + 64;
#pragma unroll
            for (int i = 0; i < 2; ++i) {
                const int R = (w * 2 + i) * 8 + lr;
                async16(krowbase + (size_t)(j0n + R) * 64 + ((lc ^ (R & 7)) * 8), &Ks[(w * 2 + i) * 512]);
            }
            // 8 chunks of 8 rows over 4 waves: chunks w*2 and w*2+1
#pragma unroll
            for (int i = 0; i < 2; ++i) {
                const int cc = w * 2 + i;                 // 0..7
                const int r = cc * 8 + lr;                // 0..63 within new half
                int gl = l_lo + 128 + r; gl = gl > 1023 ? 1023 : gl;
                async16(prowbase + (size_t)gl * 64 + ((lc ^ (r & 7)) * 8),
                        &Ps2[jt & 1][cc * 512]);
            }
        }

        // band + Bv -> Band2, pre-shifted: Band2[row][jp], jp = col + ilw - 15
#pragma unroll
        for (int u = 0; u < 5; ++u) {
#pragma unroll
            for (int r2 = 0; r2 < 4; ++r2) {
                const int ilw = fr_q * 4 + r2;
                const int jp = u * 16 + fr_row + ilw - 15;
                if (jp >= 0 && jp < 64) {
                    const int row = w * 16 + ilw;
                    Band2[row * 64 + (jp ^ ((row & 7) << 3))] = bd[u][r2] + bvv[u];
                }
            }
        }

        // scores + in-lane partial max (mask only on diagonal tile)
        const bool diag = (jt == bx);
        float p[4][4], mt[4];
#pragma unroll
        for (int r2 = 0; r2 < 4; ++r2) mt[r2] = -1e30f;
#pragma unroll
        for (int tt = 0; tt < 4; ++tt) {
            const int jp = tt * 16 + fr_row;
            const int jj = j0 + jp;
#pragma unroll
            for (int r2 = 0; r2 < 4; ++r2) {
                const int ilw = fr_q * 4 + r2;
                const int row = w * 16 + ilw;
                const float band = Band2[row * 64 + (jp ^ ((row & 7) << 3))];
                float sv = qk[tt][r2] + band + uv[tt];
                if (diag) { const int ii = i0 + row; sv = (jj <= ii) ? sv : -1e30f; }
                p[tt][r2] = sv;
                mt[r2] = fmaxf(mt[r2], sv);
            }
        }
        // row max via DPP (VALU, no LDS round-trips)
#pragma unroll
        for (int r2 = 0; r2 < 4; ++r2) mt[r2] = row_max16(mt[r2]);

        // rescale only when the tile max actually grew (wave-uniform branch)
        bool grow = false;
#pragma unroll
        for (int r2 = 0; r2 < 4; ++r2) grow = grow || (mt[r2] > m_run[r2]);
        if (__any(grow)) {
#pragma unroll
            for (int r2 = 0; r2 < 4; ++r2) {
                const float mn = fmaxf(m_run[r2], mt[r2]);
                const float alpha = __expf(m_run[r2] - mn);
                m_run[r2] = mn;
                l_run[r2] *= alpha;
#pragma unroll
                for (int dt = 0; dt < 4; ++dt) o_acc[dt][r2] *= alpha;
            }
        }

        // exp + per-lane l partials (cross-lane sum deferred to epilogue)
#pragma unroll
        for (int r2 = 0; r2 < 4; ++r2) {
            float ls = 0.f;
#pragma unroll
            for (int tt = 0; tt < 4; ++tt) { p[tt][r2] = __expf(p[tt][r2] - m_run[r2]); ls += p[tt][r2]; }
            l_run[r2] += ls;
        }

        // probs -> Pls (aliases Band2, wave-local rows, swizzled, stride 128 sh)
#pragma unroll
        for (int tt = 0; tt < 4; ++tt)
#pragma unroll
            for (int r2 = 0; r2 < 4; ++r2) {
                const int row = w * 16 + fr_q * 4 + r2;
                Pls[row * 128 + ((tt * 16 + fr_row) ^ ((row & 7) << 3))] = f2bf(p[tt][r2]);
            }

        // O += P @ V  (Pls wave-local; V in registers -- NO barrier needed)
        __builtin_amdgcn_s_setprio(1);
#pragma unroll
        for (int c = 0; c < 2; ++c) {
            const int ks = c * 32;
            const int prow = w * 16 + fr_row;
            short8 pa = *(const short8*)&Pls[prow * 128 + ((ks + fr_k) ^ ((prow & 7) << 3))];
#pragma unroll
            for (int dt = 0; dt < 4; ++dt) {
                short8 vf = (c == 0) ? vregA[dt] : vregB[dt];
                o_acc[dt] = __builtin_amdgcn_mfma_f32_16x16x32_bf16(pa, vf, o_acc[dt], 0, 0, 0);
            }
        }
        __builtin_amdgcn_s_setprio(0);
    }

    // epilogue: ONE cross-lane sum reduce for l, then write tile
    float lf[4];
#pragma unroll
    for (int r2 = 0; r2 < 4; ++r2) lf[r2] = row_sum16(l_run[r2]);
#pragma unroll
    for (int dt = 0; dt < 4; ++dt) {
        const int d = dt * 16 + fr_row;
#pragma unroll
        for (int r2 = 0; r2 < 4; ++r2) {
            const int ii = i0 + w * 16 + fr_q * 4 + r2;
            const float val = o_acc[dt][r2] / lf[r2];
            vw[(((size_t)b * 1024 + ii) * 16 + h) * 64 + d] = f2bf(val);
        }
    }
}

extern "C" void kernel_launch(void* const* d_in, const int* in_sizes, int n_in,
                              void* d_out, int out_size, void* d_ws, size_t ws_size,
                              hipStream_t stream) {
    (void)in_sizes; (void)n_in; (void)out_size; (void)ws_size;
    const float* x     = (const float*)d_in[0];
    const float* Wq    = (const float*)d_in[1];
    const float* bq    = (const float*)d_in[2];
    const float* Wk    = (const float*)d_in[3];
    const float* bk    = (const float*)d_in[4];
    const float* Wv    = (const float*)d_in[5];
    const float* bvv   = (const float*)d_in[6];
    const float* Wr    = (const float*)d_in[7];
    const float* br    = (const float*)d_in[8];
    const float* rel_u = (const float*)d_in[9];
    const float* rel_v = (const float*)d_in[10];
    const float* Wo    = (const float*)d_in[11];
    const float* bo    = (const float*)d_in[12];
    const float* relpos= (const float*)d_in[13];

    // ---- workspace layout (~42.9 MiB; proven >= 44.3 available) ----
    const size_t MEG = 1 << 20;
    short* ws    = (short*)d_ws;
    short* vw_ws = ws;                 // 4M sh
    short* wqbf  = ws + 4 * MEG;       // 1M sh
    short* wkbf  = ws + 5 * MEG;
    short* wvbf  = ws + 6 * MEG;
    short* rbf   = ws + 7 * MEG;       // 1M sh
    short* q_ws  = ws + 8 * MEG;       // 4M sh
    short* k_ws  = ws + 12 * MEG;
    short* v_ws  = ws + 16 * MEG;      // (b,H,dk,s)
    short* p_ws  = ws + 20 * MEG;      // 1M sh
    float* U_ws  = (float*)(ws + 21 * MEG);   // 65536 fl
    float* Bv_ws = U_ws + 65536;       // 16384 fl
    float* ub    = Bv_ws + 16384;      // 16 fl
    float* vb    = ub + 16;            // 16 fl
    short* wrubf = (short*)(vb + 16);  // 128*1024 sh (rows 16..127 padding)
    short* wrvbf = wrubf + 131072;     // 128*1024 sh
    unsigned int* qcount = (unsigned int*)(wrvbf + 131072);

    // 1) convert Wq, Wk, Wv, R(rows 1..1024) to bf16 + fold rel_u/rel_v
    //    (x stays fp32 -- converted in-kernel by gemm_fused)
    CvtJobs cj;
    cj.src[0] = Wq;            cj.dst[0] = wqbf; cj.n8[0] = MEG / 8;
    cj.src[1] = Wk;            cj.dst[1] = wkbf; cj.n8[1] = MEG / 8;
    cj.src[2] = Wv;            cj.dst[2] = wvbf; cj.n8[2] = MEG / 8;
    cj.src[3] = relpos + 1024; cj.dst[3] = rbf;  cj.n8[3] = MEG / 8;
    cvtprep_kernel<<<dim3(2048, 5), 256, 0, stream>>>(cj, Wr, br, rel_u, rel_v,
                                                      wrubf, wrvbf, ub, vb, qcount);

    // 2) QKV + P + U + Bv projections in ONE launch (grid 32x28)
    Tasks t1;
    t1.t[0] = {wqbf,  bq,  q_ws, 0};
    t1.t[1] = {wkbf,  bk,  k_ws, 0};
    t1.t[2] = {wvbf,  bvv, v_ws, 1};
    t1.t[3] = {wkbf,  bk,  p_ws, 2};
    t1.t[4] = {wrubf, ub,  (short*)U_ws,  3};
    t1.t[5] = {wrvbf, vb,  (short*)Bv_ws, 4};
    gemm_fused<<<dim3(32, 28), 256, 0, stream>>>(x, rbf, t1);

    // 3) flash attention (1024 blocks, longest-first LPT work queue)
    attn_kernel<<<dim3(1024), 256, 0, stream>>>(q_ws, k_ws, v_ws, p_ws, U_ws,
                                                Bv_ws, vw_ws, qcount);

    // 4) output projection -> fp32 (Wo fp32 converted in-kernel)
    gemm_out<<<dim3(32, 16), 256, 0, stream>>>(vw_ws, Wo, bo, (float*)d_out);
}

// Round 18
// 253.999 us; speedup vs baseline: 1.1161x; 1.1161x over previous
//
#include <hip/hip_runtime.h>

// ---------------------------------------------------------------------------
// Transformer-XL relative-position MHA.  b=4, s=1024, H=16, dk=64.
// Inputs fp32, OUTPUT fp32.  Round 27 = R16 config (revert R17's in-kernel
// x conversion: it exposed synchronous load latency in gemm_fused, 94us).
//  - cvtprep converts x/Wq/Wk/Wv/R to bf16 at full HBM BW (5 jobs).
//  - attn: sliding-P ring, prescale folded into q/U/Bv, diag-only mask,
//    longest-first LPT queue, V-hoist pre-B2, setprio (best attn: 74.5us).
//  - gemm_fused: BK=64, 2-barrier, swizzled, async16 both operands.
// ---------------------------------------------------------------------------

typedef __attribute__((ext_vector_type(8))) short short8;
typedef __attribute__((ext_vector_type(4))) float f32x4;

#define KD 1024

__device__ __forceinline__ float bf2f(short s) {
    unsigned int u = ((unsigned int)(unsigned short)s) << 16;
    return __builtin_bit_cast(float, u);
}
__device__ __forceinline__ short f2bf(float f) {
    unsigned int u = __builtin_bit_cast(unsigned int, f);
    u = u + 0x7fffu + ((u >> 16) & 1u);
    return (short)(u >> 16);
}
__device__ __forceinline__ short8 cvt8(const float* p) {
    f32x4 a = *(const f32x4*)p;
    f32x4 b = *(const f32x4*)(p + 4);
    short8 r;
    r[0] = f2bf(a[0]); r[1] = f2bf(a[1]); r[2] = f2bf(a[2]); r[3] = f2bf(a[3]);
    r[4] = f2bf(b[0]); r[5] = f2bf(b[1]); r[6] = f2bf(b[2]); r[7] = f2bf(b[3]);
    return r;
}

typedef const __attribute__((address_space(1))) void gas_void;
typedef __attribute__((address_space(3))) void las_void;
__device__ __forceinline__ void async16(const void* g, void* l) {
    __builtin_amdgcn_global_load_lds((gas_void*)g, (las_void*)l, 16, 0, 0);
}

// ---- DPP row (16-lane) reductions: VALU pipe, no LDS ----
template <int CTRL>
__device__ __forceinline__ float dpp_rotf(float v) {
    return __builtin_bit_cast(float, __builtin_amdgcn_update_dpp(
        0, __builtin_bit_cast(int, v), CTRL, 0xF, 0xF, true));
}
__device__ __forceinline__ float row_max16(float v) {
    v = fmaxf(v, dpp_rotf<0x128>(v));   // row_ror:8
    v = fmaxf(v, dpp_rotf<0x124>(v));   // row_ror:4
    v = fmaxf(v, dpp_rotf<0x122>(v));   // row_ror:2
    v = fmaxf(v, dpp_rotf<0x121>(v));   // row_ror:1
    return v;
}
__device__ __forceinline__ float row_sum16(float v) {
    v += dpp_rotf<0x128>(v);
    v += dpp_rotf<0x124>(v);
    v += dpp_rotf<0x122>(v);
    v += dpp_rotf<0x121>(v);
    return v;
}

// ---------------- fused cvt (y<5) + prep (y==5) ----------------
struct CvtJobs { const float* src[5]; short* dst[5]; int n8[5]; int njobs; };

__global__ __launch_bounds__(256) void cvtprep_kernel(
    CvtJobs j,
    const float* __restrict__ Wr, const float* __restrict__ br,
    const float* __restrict__ ru, const float* __restrict__ rv,
    short* __restrict__ wrubf, short* __restrict__ wrvbf,
    float* __restrict__ ub, float* __restrict__ vb,
    unsigned int* __restrict__ qcount) {
    const int y = blockIdx.y, tid = threadIdx.x;
    if (y < 5) {
        const int t = blockIdx.x * 256 + tid;
        if (t < j.n8[y]) *(short8*)&j.dst[y][t * 8] = cvt8(&j.src[y][t * 8]);
        return;
    }
    // prep: fold rel_u/rel_v into Wr; emit bf16 weight rows [h][k]
    if (blockIdx.x >= 64) return;
    if (blockIdx.x == 0 && tid == 0) *qcount = 0;   // init attn work queue
    const int idx = blockIdx.x * 256 + tid;  // 0..16383
    const int h = idx >> 10, k = idx & 1023;
    float su = 0.f, sv = 0.f;
    for (int d = 0; d < 64; ++d) {
        const float w = Wr[(size_t)(h * 64 + d) * 1024 + k];
        su += ru[h * 64 + d] * w;
        sv += rv[h * 64 + d] * w;
    }
    wrubf[h * 1024 + k] = f2bf(su);
    wrvbf[h * 1024 + k] = f2bf(sv);
    if (idx < 16) {
        float bu = 0.f, bv2 = 0.f;
        for (int d = 0; d < 64; ++d) {
            bu += ru[idx * 64 + d] * br[idx * 64 + d];
            bv2 += rv[idx * 64 + d] * br[idx * 64 + d];
        }
        ub[idx] = bu; vb[idx] = bv2;
    }
}

// ---------------- fused projection GEMM (BK=64, 2 barriers, swizzled) ----------------
struct Task { const short* W; const float* bias; short* out; int mode; };
struct Tasks { Task t[6]; };

// y<24: QKV from A0[4096,1024]; y=24..25: P from A1[1024,1024];
// y=26: U from A0 (N=16, fp32 out); y=27 (x<8): Bv from A1 (N=16, fp32 out).
// mode 0: (b,H,s,dk) bf16  1: (b,H,dk,s) bf16  2: (H,s,dk) bf16
// mode 3: U f32   4: Bv f32.   q/U/Bv epilogues scaled by 0.125 (1/sqrt dk).
__global__ __launch_bounds__(256) void gemm_fused(
    const short* __restrict__ A0, const short* __restrict__ A1, Tasks tasks) {
    __shared__ short As[128 * 64];
    __shared__ short Bs[128 * 64];
    const int tid  = threadIdx.x;
    const int wave = tid >> 6, lane = tid & 63;
    const int y    = blockIdx.y;
    const short* A; int m0, n0, tksel;
    if (y < 24)      { A = A0; m0 = blockIdx.x * 128; n0 = (y & 7) * 128; tksel = y >> 3; }
    else if (y < 26) { const int q = (y - 24) * 32 + blockIdx.x;
                       A = A1; m0 = (q >> 3) * 128; n0 = (q & 7) * 128; tksel = 3; }
    else if (y == 26){ A = A0; m0 = blockIdx.x * 128; n0 = 0; tksel = 4; }
    else             { if (blockIdx.x >= 8) return;
                       A = A1; m0 = blockIdx.x * 128; n0 = 0; tksel = 5; }
    const Task tk  = tasks.t[tksel];
    const short* W = tk.W;
    const float oscale = (tksel == 0 || tksel >= 4) ? 0.125f : 1.0f;

    f32x4 acc[4][4];
#pragma unroll
    for (int i = 0; i < 4; ++i)
#pragma unroll
        for (int j = 0; j < 4; ++j) acc[i][j] = (f32x4){0.f, 0.f, 0.f, 0.f};

    const int wm = wave >> 1, wn = wave & 1;
    const int fr_row = lane & 15, fr_k = (lane >> 4) * 8;

    for (int kt = 0; kt < KD / 64; ++kt) {
        const int k0 = kt * 64;
        // staging: linear LDS dest + inverse-XOR-swizzled global source col
#pragma unroll
        for (int i = 0; i < 4; ++i) {
            const int c = (i * 4 + wave) * 64 + lane;
            const int row = c >> 3, col = ((c & 7) ^ (row & 7)) * 8;
            async16(A + (size_t)(m0 + row) * KD + k0 + col, &As[(i * 4 + wave) * 512]);
            async16(W + (size_t)(n0 + row) * KD + k0 + col, &Bs[(i * 4 + wave) * 512]);
        }
        __syncthreads();
#pragma unroll
        for (int ks = 0; ks < 64; ks += 32) {
            const int un = (ks + fr_k) >> 3;
            short8 a[4], bfrag[4];
#pragma unroll
            for (int mi = 0; mi < 4; ++mi) {
                const int R = wm * 64 + mi * 16 + fr_row;
                a[mi] = *(const short8*)&As[R * 64 + ((un ^ (R & 7)) << 3)];
            }
#pragma unroll
            for (int ni = 0; ni < 4; ++ni) {
                const int R = wn * 64 + ni * 16 + fr_row;
                bfrag[ni] = *(const short8*)&Bs[R * 64 + ((un ^ (R & 7)) << 3)];
            }
#pragma unroll
            for (int mi = 0; mi < 4; ++mi)
#pragma unroll
                for (int ni = 0; ni < 4; ++ni)
                    acc[mi][ni] = __builtin_amdgcn_mfma_f32_16x16x32_bf16(a[mi], bfrag[ni], acc[mi][ni], 0, 0, 0);
        }
        __syncthreads();
    }

    const int mode = tk.mode;
#pragma unroll
    for (int ni = 0; ni < 4; ++ni) {
        const int n = n0 + wn * 64 + ni * 16 + fr_row;
        if (mode >= 3 && n >= 16) continue;
        const float bias = tk.bias[n];
#pragma unroll
        for (int mi = 0; mi < 4; ++mi) {
            const int mbase = m0 + wm * 64 + mi * 16 + (lane >> 4) * 4;
#pragma unroll
            for (int r = 0; r < 4; ++r) {
                const int m = mbase + r;
                const float val = (acc[mi][ni][r] + bias) * oscale;
                if (mode == 0)
                    tk.out[(((size_t)(m >> 10) * 16 + (n >> 6)) * 1024 + (m & 1023)) * 64 + (n & 63)] = f2bf(val);
                else if (mode == 1)
                    tk.out[(((size_t)(m >> 10) * 16 + (n >> 6)) * 64 + (n & 63)) * 1024 + (m & 1023)] = f2bf(val);
                else if (mode == 2)
                    tk.out[((size_t)(n >> 6) * 1024 + m) * 64 + (n & 63)] = f2bf(val);
                else if (mode == 3)
                    ((float*)tk.out)[((size_t)(m >> 10) * 16 + n) * 1024 + (m & 1023)] = val;
                else
                    ((float*)tk.out)[(size_t)n * 1024 + m] = val;
            }
        }
    }
}

// Final GEMM: A bf16 (vw), W = Wo FP32 (converted on the fly into swizzled
// bf16 LDS), out FP32 row-major.  128x64 tile, grid 32x16 = 512 blocks.
__global__ __launch_bounds__(256) void gemm_out(const short* __restrict__ A,
                                                const float* __restrict__ W,
                                                const float* __restrict__ bias,
                                                float* __restrict__ out) {
    __shared__ short As[128 * 64];
    __shared__ short Bs[64 * 64];
    const int tid  = threadIdx.x;
    const int wave = tid >> 6, lane = tid & 63;
    const int m0   = blockIdx.x * 128;
    const int n0   = blockIdx.y * 64;

    f32x4 acc[4][2];
#pragma unroll
    for (int i = 0; i < 4; ++i)
#pragma unroll
        for (int j = 0; j < 2; ++j) acc[i][j] = (f32x4){0.f, 0.f, 0.f, 0.f};

    const int wm = wave >> 1, wn = wave & 1;
    const int fr_row = lane & 15, fr_k = (lane >> 4) * 8;
    const int brow = tid >> 2, bcol16 = (tid & 3) * 16;   // B staging geometry

    for (int kt = 0; kt < KD / 64; ++kt) {
        const int k0 = kt * 64;
        // A: async16 staging, swizzled source col
#pragma unroll
        for (int i = 0; i < 4; ++i) {
            const int c = (i * 4 + wave) * 64 + lane;
            const int row = c >> 3, col = ((c & 7) ^ (row & 7)) * 8;
            async16(A + (size_t)(m0 + row) * KD + k0 + col, &As[(i * 4 + wave) * 512]);
        }
        // B: reg-staged Wo fp32 -> bf16, XOR-swizzled units (16B units)
        {
            const float* wp = W + (size_t)(n0 + brow) * KD + k0 + bcol16;
            short8 v0 = cvt8(wp);
            short8 v1 = cvt8(wp + 8);
            const int u0 = bcol16 >> 3;     // 0,2,4,6
            short* dst = &Bs[brow * 64];
            *(short8*)&dst[((u0 ^ (brow & 7)) << 3)]       = v0;
            *(short8*)&dst[(((u0 + 1) ^ (brow & 7)) << 3)] = v1;
        }
        __syncthreads();
#pragma unroll
        for (int ks = 0; ks < 64; ks += 32) {
            const int un = (ks + fr_k) >> 3;
            short8 a[4], bfrag[2];
#pragma unroll
            for (int mi = 0; mi < 4; ++mi) {
                const int R = wm * 64 + mi * 16 + fr_row;
                a[mi] = *(const short8*)&As[R * 64 + ((un ^ (R & 7)) << 3)];
            }
#pragma unroll
            for (int ni = 0; ni < 2; ++ni) {
                const int R = wn * 32 + ni * 16 + fr_row;
                bfrag[ni] = *(const short8*)&Bs[R * 64 + ((un ^ (R & 7)) << 3)];
            }
#pragma unroll
            for (int mi = 0; mi < 4; ++mi)
#pragma unroll
                for (int ni = 0; ni < 2; ++ni)
                    acc[mi][ni] = __builtin_amdgcn_mfma_f32_16x16x32_bf16(a[mi], bfrag[ni], acc[mi][ni], 0, 0, 0);
        }
        __syncthreads();
    }

#pragma unroll
    for (int ni = 0; ni < 2; ++ni) {
        const int n = n0 + wn * 32 + ni * 16 + fr_row;
        const float bv = bias[n];
#pragma unroll
        for (int mi = 0; mi < 4; ++mi) {
            const int mbase = m0 + wm * 64 + mi * 16 + (lane >> 4) * 4;
#pragma unroll
            for (int r = 0; r < 4; ++r)
                out[(size_t)(mbase + r) * 1024 + n] = acc[mi][ni][r] + bv;
        }
    }
}

// ---------------- flash attention (sliding-P ring + LPT queue) ----------------
// LDS (exactly 40,960 B):
//   Ks[64x64] sh (swizzled, gload_lds-staged)             8,192 B
//   Ps2[2][64x64] sh ring (swizzled; window slides 64/iter) 16,384 B
//   Band2[64x64] f32, pre-shifted [qrow][j], swizzled     16,384 B (Pls alias)
// Iter jt reads P rows [l_lo,l_lo+128): lower half in slot jt&1, upper in
// (jt+1)&1; prefetch stages only the NEW 64 rows into slot jt&1 (post-B2).
// Longest-first LPT queue; V hoisted pre-B2; setprio around MFMA clusters;
// scores pre-scaled (0.125 folded into q/U/Bv); mask only on diagonal tile.
__global__ __launch_bounds__(256) void attn_kernel(
    const short* __restrict__ q_ws, const short* __restrict__ k_ws,
    const short* __restrict__ v_ws, const short* __restrict__ p_ws,
    const float* __restrict__ U_ws, const float* __restrict__ Bv_ws,
    short* __restrict__ vw, unsigned int* __restrict__ qcount) {
    __shared__ short Ks[64 * 64];
    __shared__ short Ps2[2][64 * 64];
    __shared__ float Band2[64 * 64];
    short* Pls = (short*)Band2;        // stride 128 sh, swizzled

    const int tid = threadIdx.x;
    const int w = tid >> 6, lane = tid & 63;

    // ---- pop work item (longest-first) ----
    if (tid == 0) *(int*)&Band2[0] = (int)atomicAdd(qcount, 1u);
    __syncthreads();
    const int it = *(const int*)&Band2[0];
    const int bx = 15 - (it >> 6);            // 64 longest items first
    const int g  = it & 63;                   // (b,h) group
    const int h = g & 15, b = g >> 4;
    const int i0 = bx * 64;
    const int bh = b * 16 + h;
    const int fr_row = lane & 15, fr_q = lane >> 4, fr_k = fr_q * 8;
    const int lr = lane >> 3, lc = lane & 7;  // staging geometry (8 rows/1KB chunk)

    short8 qfrag[2];
    {
        const short* qrow = q_ws + ((size_t)bh * 1024 + i0 + w * 16 + fr_row) * 64;
        qfrag[0] = *(const short8*)&qrow[fr_k];
        qfrag[1] = *(const short8*)&qrow[32 + fr_k];
    }

    float m_run[4], l_run[4];
    f32x4 o_acc[4];
#pragma unroll
    for (int r2 = 0; r2 < 4; ++r2) { m_run[r2] = -1e30f; l_run[r2] = 0.f; }
#pragma unroll
    for (int dt = 0; dt < 4; ++dt) o_acc[dt] = (f32x4){0.f, 0.f, 0.f, 0.f};

    const int tt0 = 3 - w;
    const short* krowbase = k_ws + (size_t)bh * 1024 * 64;  // (j, d)
    const short* vrowbase = v_ws + (size_t)bh * 64 * 1024;  // (d, j)
    const short* prowbase = p_ws + (size_t)h * 1024 * 64;   // (l, d)

    // ---- prologue: issue K(0) + BOTH P halves for iter 0 ----
    {
        const int l_lo0 = 960 - i0;
#pragma unroll
        for (int i = 0; i < 2; ++i) {
            const int R = (w * 2 + i) * 8 + lr;
            async16(krowbase + (size_t)R * 64 + ((lc ^ (R & 7)) * 8), &Ks[(w * 2 + i) * 512]);
        }
#pragma unroll
        for (int i = 0; i < 4; ++i) {
            const int c = w * 4 + i;          // chunk 0..15; slot c>>3, 8 rows each
            const int R = c * 8 + lr;         // 0..127
            int gl = l_lo0 + R; gl = gl > 1023 ? 1023 : gl;
            async16(prowbase + (size_t)gl * 64 + ((lc ^ (R & 7)) * 8),
                    &Ps2[c >> 3][(c & 7) * 512]);
        }
    }

    for (int jt = 0; jt <= bx; ++jt) {
        const int j0 = jt * 64;
        const int l_lo = j0 - i0 + 960;

        // B1: K(jt) + P halves landed + all waves synced
        asm volatile("s_waitcnt vmcnt(0)" ::: "memory");
        __builtin_amdgcn_s_barrier();
        asm volatile("" ::: "memory");

        // hoisted U / Bv loads (pre-scaled by 0.125 in projection)
        float uv[4];
#pragma unroll
        for (int tt = 0; tt < 4; ++tt) uv[tt] = U_ws[bh * 1024 + j0 + tt * 16 + fr_row];
        float bvv[5];
#pragma unroll
        for (int u = 0; u < 5; ++u) {
            int l = l_lo + (tt0 + u) * 16 + fr_row;
            l = l > 1023 ? 1023 : l;
            bvv[u] = Bv_ws[h * 1024 + l];
        }

        // QK^T + relative-band MFMAs (swizzled LDS reads; P via 2-slot ring)
        f32x4 qk[4], bd[5];
#pragma unroll
        for (int tt = 0; tt < 4; ++tt) qk[tt] = (f32x4){0.f, 0.f, 0.f, 0.f};
#pragma unroll
        for (int u = 0; u < 5; ++u) bd[u] = (f32x4){0.f, 0.f, 0.f, 0.f};

        __builtin_amdgcn_s_setprio(1);
#pragma unroll
        for (int c = 0; c < 2; ++c) {
            const int col = c * 4 + fr_q;
#pragma unroll
            for (int tt = 0; tt < 4; ++tt) {
                const int R = tt * 16 + fr_row;
                short8 kf = *(const short8*)&Ks[R * 64 + ((col ^ (R & 7)) << 3)];
                qk[tt] = __builtin_amdgcn_mfma_f32_16x16x32_bf16(qfrag[c], kf, qk[tt], 0, 0, 0);
            }
#pragma unroll
            for (int u = 0; u < 5; ++u) {
                const int R = (tt0 + u) * 16 + fr_row;      // 0..127 in window
                const int slot = (jt + (R >> 6)) & 1;
                const int r6 = R & 63;
                short8 pf = *(const short8*)&Ps2[slot][r6 * 64 + ((col ^ (r6 & 7)) << 3)];
                bd[u] = __builtin_amdgcn_mfma_f32_16x16x32_bf16(qfrag[c], pf, bd[u], 0, 0, 0);
            }
        }
        __builtin_amdgcn_s_setprio(0);

        // V global->reg, issued BEFORE B2 (global-only: no barrier hazard)
        const short* vjt = vrowbase + j0;
        short8 vregA[4], vregB[4];
#pragma unroll
        for (int dt = 0; dt < 4; ++dt)
            vregA[dt] = *(const short8*)&vjt[(size_t)(dt * 16 + fr_row) * 1024 + fr_k];
#pragma unroll
        for (int dt = 0; dt < 4; ++dt)
            vregB[dt] = *(const short8*)&vjt[(size_t)(dt * 16 + fr_row) * 1024 + 32 + fr_k];

        // B2: all waves done reading Ks/Ps2 -> safe to overwrite via prefetch
        asm volatile("" ::: "memory");
        __builtin_amdgcn_s_barrier();
        asm volatile("" ::: "memory");

        if (jt < bx) {   // prefetch K(jt+1) + ONLY the new P half
            const int j0n = j0 + 64;
#pragma unroll
            for (int i = 0; i < 2; ++i) {
                const int R = (w * 2 + i) * 8 + lr;
                async16(krowbase + (size_t)(j0n + R) * 64 + ((lc ^ (R & 7)) * 8), &Ks[(w * 2 + i) * 512]);
            }
            // 8 chunks of 8 rows over 4 waves: chunks w*2 and w*2+1
#pragma unroll
            for (int i = 0; i < 2; ++i) {
                const int cc = w * 2 + i;                 // 0..7
                const int r = cc * 8 + lr;                // 0..63 within new half
                int gl = l_lo + 128 + r; gl = gl > 1023 ? 1023 : gl;
                async16(prowbase + (size_t)gl * 64 + ((lc ^ (r & 7)) * 8),
                        &Ps2[jt & 1][cc * 512]);
            }
        }

        // band + Bv -> Band2, pre-shifted: Band2[row][jp], jp = col + ilw - 15
#pragma unroll
        for (int u = 0; u < 5; ++u) {
#pragma unroll
            for (int r2 = 0; r2 < 4; ++r2) {
                const int ilw = fr_q * 4 + r2;
                const int jp = u * 16 + fr_row + ilw - 15;
                if (jp >= 0 && jp < 64) {
                    const int row = w * 16 + ilw;
                    Band2[row * 64 + (jp ^ ((row & 7) << 3))] = bd[u][r2] + bvv[u];
                }
            }
        }

        // scores + in-lane partial max (mask only on diagonal tile)
        const bool diag = (jt == bx);
        float p[4][4], mt[4];
#pragma unroll
        for (int r2 = 0; r2 < 4; ++r2) mt[r2] = -1e30f;
#pragma unroll
        for (int tt = 0; tt < 4; ++tt) {
            const int jp = tt * 16 + fr_row;
            const int jj = j0 + jp;
#pragma unroll
            for (int r2 = 0; r2 < 4; ++r2) {
                const int ilw = fr_q * 4 + r2;
                const int row = w * 16 + ilw;
                const float band = Band2[row * 64 + (jp ^ ((row & 7) << 3))];
                float sv = qk[tt][r2] + band + uv[tt];
                if (diag) { const int ii = i0 + row; sv = (jj <= ii) ? sv : -1e30f; }
                p[tt][r2] = sv;
                mt[r2] = fmaxf(mt[r2], sv);
            }
        }
        // row max via DPP (VALU, no LDS round-trips)
#pragma unroll
        for (int r2 = 0; r2 < 4; ++r2) mt[r2] = row_max16(mt[r2]);

        // rescale only when the tile max actually grew (wave-uniform branch)
        bool grow = false;
#pragma unroll
        for (int r2 = 0; r2 < 4; ++r2) grow = grow || (mt[r2] > m_run[r2]);
        if (__any(grow)) {
#pragma unroll
            for (int r2 = 0; r2 < 4; ++r2) {
                const float mn = fmaxf(m_run[r2], mt[r2]);
                const float alpha = __expf(m_run[r2] - mn);
                m_run[r2] = mn;
                l_run[r2] *= alpha;
#pragma unroll
                for (int dt = 0; dt < 4; ++dt) o_acc[dt][r2] *= alpha;
            }
        }

        // exp + per-lane l partials (cross-lane sum deferred to epilogue)
#pragma unroll
        for (int r2 = 0; r2 < 4; ++r2) {
            float ls = 0.f;
#pragma unroll
            for (int tt = 0; tt < 4; ++tt) { p[tt][r2] = __expf(p[tt][r2] - m_run[r2]); ls += p[tt][r2]; }
            l_run[r2] += ls;
        }

        // probs -> Pls (aliases Band2, wave-local rows, swizzled, stride 128 sh)
#pragma unroll
        for (int tt = 0; tt < 4; ++tt)
#pragma unroll
            for (int r2 = 0; r2 < 4; ++r2) {
                const int row = w * 16 + fr_q * 4 + r2;
                Pls[row * 128 + ((tt * 16 + fr_row) ^ ((row & 7) << 3))] = f2bf(p[tt][r2]);
            }

        // O += P @ V  (Pls wave-local; V in registers -- NO barrier needed)
        __builtin_amdgcn_s_setprio(1);
#pragma unroll
        for (int c = 0; c < 2; ++c) {
            const int ks = c * 32;
            const int prow = w * 16 + fr_row;
            short8 pa = *(const short8*)&Pls[prow * 128 + ((ks + fr_k) ^ ((prow & 7) << 3))];
#pragma unroll
            for (int dt = 0; dt < 4; ++dt) {
                short8 vf = (c == 0) ? vregA[dt] : vregB[dt];
                o_acc[dt] = __builtin_amdgcn_mfma_f32_16x16x32_bf16(pa, vf, o_acc[dt], 0, 0, 0);
            }
        }
        __builtin_amdgcn_s_setprio(0);
    }

    // epilogue: ONE cross-lane sum reduce for l, then write tile
    float lf[4];
#pragma unroll
    for (int r2 = 0; r2 < 4; ++r2) lf[r2] = row_sum16(l_run[r2]);
#pragma unroll
    for (int dt = 0; dt < 4; ++dt) {
        const int d = dt * 16 + fr_row;
#pragma unroll
        for (int r2 = 0; r2 < 4; ++r2) {
            const int ii = i0 + w * 16 + fr_q * 4 + r2;
            const float val = o_acc[dt][r2] / lf[r2];
            vw[(((size_t)b * 1024 + ii) * 16 + h) * 64 + d] = f2bf(val);
        }
    }
}

extern "C" void kernel_launch(void* const* d_in, const int* in_sizes, int n_in,
                              void* d_out, int out_size, void* d_ws, size_t ws_size,
                              hipStream_t stream) {
    (void)in_sizes; (void)n_in; (void)out_size; (void)ws_size;
    const float* x     = (const float*)d_in[0];
    const float* Wq    = (const float*)d_in[1];
    const float* bq    = (const float*)d_in[2];
    const float* Wk    = (const float*)d_in[3];
    const float* bk    = (const float*)d_in[4];
    const float* Wv    = (const float*)d_in[5];
    const float* bvv   = (const float*)d_in[6];
    const float* Wr    = (const float*)d_in[7];
    const float* br    = (const float*)d_in[8];
    const float* rel_u = (const float*)d_in[9];
    const float* rel_v = (const float*)d_in[10];
    const float* Wo    = (const float*)d_in[11];
    const float* bo    = (const float*)d_in[12];
    const float* relpos= (const float*)d_in[13];

    // ---- workspace layout (~42.9 MiB; proven >= 44.3 available) ----
    const size_t MEG = 1 << 20;
    short* ws    = (short*)d_ws;
    short* xbf   = ws;                 // 4M sh  (aliased with vw: xbf dead pre-attn)
    short* vw_ws = ws;
    short* wqbf  = ws + 4 * MEG;       // 1M sh
    short* wkbf  = ws + 5 * MEG;
    short* wvbf  = ws + 6 * MEG;
    short* rbf   = ws + 7 * MEG;       // 1M sh
    short* q_ws  = ws + 8 * MEG;       // 4M sh
    short* k_ws  = ws + 12 * MEG;
    short* v_ws  = ws + 16 * MEG;      // (b,H,dk,s)
    short* p_ws  = ws + 20 * MEG;      // 1M sh
    float* U_ws  = (float*)(ws + 21 * MEG);   // 65536 fl
    float* Bv_ws = U_ws + 65536;       // 16384 fl
    float* ub    = Bv_ws + 16384;      // 16 fl
    float* vb    = ub + 16;            // 16 fl
    short* wrubf = (short*)(vb + 16);  // 128*1024 sh (rows 16..127 padding)
    short* wrvbf = wrubf + 131072;     // 128*1024 sh
    unsigned int* qcount = (unsigned int*)(wrvbf + 131072);

    // 1) convert x, Wq, Wk, Wv, R(rows 1..1024) to bf16 + fold rel_u/rel_v
    CvtJobs cj;
    cj.src[0] = x;             cj.dst[0] = xbf;  cj.n8[0] = (4 * MEG) / 8;
    cj.src[1] = Wq;            cj.dst[1] = wqbf; cj.n8[1] = MEG / 8;
    cj.src[2] = Wk;            cj.dst[2] = wkbf; cj.n8[2] = MEG / 8;
    cj.src[3] = Wv;            cj.dst[3] = wvbf; cj.n8[3] = MEG / 8;
    cj.src[4] = relpos + 1024; cj.dst[4] = rbf;  cj.n8[4] = MEG / 8;
    cj.njobs = 5;
    cvtprep_kernel<<<dim3(2048, 6), 256, 0, stream>>>(cj, Wr, br, rel_u, rel_v,
                                                      wrubf, wrvbf, ub, vb, qcount);

    // 2) QKV + P + U + Bv projections in ONE launch (grid 32x28)
    Tasks t1;
    t1.t[0] = {wqbf,  bq,  q_ws, 0};
    t1.t[1] = {wkbf,  bk,  k_ws, 0};
    t1.t[2] = {wvbf,  bvv, v_ws, 1};
    t1.t[3] = {wkbf,  bk,  p_ws, 2};
    t1.t[4] = {wrubf, ub,  (short*)U_ws,  3};
    t1.t[5] = {wrvbf, vb,  (short*)Bv_ws, 4};
    gemm_fused<<<dim3(32, 28), 256, 0, stream>>>(xbf, rbf, t1);

    // 3) flash attention (1024 blocks, longest-first LPT work queue)
    attn_kernel<<<dim3(1024), 256, 0, stream>>>(q_ws, k_ws, v_ws, p_ws, U_ws,
                                                Bv_ws, vw_ws, qcount);

    // 4) output projection -> fp32 (Wo fp32 converted in-kernel)
    gemm_out<<<dim3(32, 16), 256, 0, stream>>>(vw_ws, Wo, bo, (float*)d_out);
}